// Round 4
// baseline (10164.275 us; speedup 1.0000x reference)
//
#include <hip/hip_runtime.h>
#include <hip/hip_cooperative_groups.h>
#include <math.h>

namespace cg = cooperative_groups;

#define NB 128      // batch
#define NT 64       // timesteps
#define NI 512      // input dim
#define NH 1024     // hidden dim
#define NO 512      // output dim
#define PONDOFF (NB*NT*NO)

// dynamic LDS: [1024][32] w_hh column-slice, XOR-swizzled, 128 KB
extern __shared__ float smem[];

// Per-group (32-block) barrier.
// Release: RELEASE atomic flag store (waitcnt + wbl2 + store to coherence point).
// Poll: fetch_add(0) RMW every iteration — RMWs execute at the coherence point
// (L3), so they ALWAYS see fresh flags (round-3 bug: relaxed loads spin on a
// stale local-L2 line; only the every-64th RMW saw the update -> ~25us/barrier).
// No cache maintenance during the spin. One ACQUIRE fence per wave afterwards.
__device__ __forceinline__ void group_barrier(unsigned* arr, int lb, unsigned gen, int tid)
{
    __syncthreads();   // each wave drains vmem (compiler emits waitcnt before s_barrier)
    if (tid == 0)
        __hip_atomic_store(&arr[lb*16], gen, __ATOMIC_RELEASE, __HIP_MEMORY_SCOPE_AGENT);
    if (tid < 32) {
        while (__hip_atomic_fetch_add(&arr[tid*16], 0u, __ATOMIC_RELAXED,
                                      __HIP_MEMORY_SCOPE_AGENT) < gen)
            __builtin_amdgcn_s_sleep(2);
    }
    __syncthreads();
    __builtin_amdgcn_fence(__ATOMIC_ACQUIRE, "agent");   // L1+L2 inv, once per wave
}

// 256 blocks x 1024 threads. 8 groups x 32 blocks; group owns 16 batch rows,
// block owns a 32-col slice. Wave w: rq=w>>2 (row quad), co=w&3 (col octet).
// Lane: up=lane&3 (col pair in octet), ks=lane>>2 (k-slice of 64).
// Halting decisions are computed REDUNDANTLY per block (identical fixed
// reduction tree -> bit-identical across blocks -> uniform control flow),
// so barriers carry only h data + one flag store.
__global__ void __launch_bounds__(1024, 1)
arnn_coop(const float* __restrict__ x, const float* __restrict__ s0,
          const float* __restrict__ w_ih, const float* __restrict__ w_hh,
          const float* __restrict__ b_ih, const float* __restrict__ b_hh,
          const float* __restrict__ w_halt, const float* __restrict__ b_halt,
          const float* __restrict__ w_out, const float* __restrict__ b_out,
          float* __restrict__ out, float* __restrict__ ws)
{
    cg::grid_group grid = cg::this_grid();
    const int tid = threadIdx.x;
    const int bid = blockIdx.x;
    const int gid = bid * 1024 + tid;

    // ws layout (floats)
    float* wihT  = ws;                       // [NI][NH]  wihT[i*NH+j] = w_ih[j][1+i]
    float* hbuf  = wihT + NI*NH;             // [3][NB][NH] 3-slot rotating h buffer
    float* habuf = hbuf + 3*NB*NH;           // [2][NB][NH] timestep-parity h_acc
    unsigned* arrA = (unsigned*)(habuf + 2*NB*NH);  // [8][32][16] flags, 64B pad

    const int gp = bid >> 5, lb = bid & 31;

    __shared__ float s_whalt[NH];            // 4 KB
    __shared__ __align__(16) unsigned char s_act[16];

    // ---- phase 0 ----
    for (int e = gid; e < NI*NH; e += 256*1024) {
        const int i = e >> 10, jj = e & 1023;
        wihT[e] = w_ih[jj*(NI+1) + 1 + i];
    }
    if (gid < 8*32*16)
        __hip_atomic_store(&arrA[gid], 0u, __ATOMIC_RELAXED, __HIP_MEMORY_SCOPE_AGENT);
    // stage this block's w_hh column slice into LDS, XOR-swizzled:
    // element (k, j) at float offset k*32 + ((j>>1)^((k>>6)&15))*2 + (j&1)
    for (int e = tid; e < 1024*32; e += 1024) {
        const int k = e & 1023, jj = e >> 10;
        const float v = w_hh[(lb*32 + jj)*NH + k];
        const int su = (jj >> 1) ^ ((k >> 6) & 15);
        smem[k*32 + su*2 + (jj & 1)] = v;
    }
    s_whalt[tid & 1023] = w_halt[tid & 1023];   // 1024 threads, 1:1
    grid.sync();

    unsigned* arr = arrA + gp*512;           // [32][16]

    const int w    = tid >> 6;
    const int lane = tid & 63;
    const int rq   = w >> 2;                 // row quad 0..3
    const int co   = w & 3;                  // col octet 0..3
    const int up   = lane & 3;               // col pair in octet
    const int ks   = lane >> 2;              // k-slice 0..15 (64 wide)
    const int u    = co*4 + up;              // col pair in block 0..15
    const int jg   = lb*32 + u*2;            // global col (pair base)
    const int b0   = gp*16 + rq*4;           // first of my 4 rows
    const bool k0  = (ks == 0);
    const int ldsb = ks*2048 + ((u ^ ks) << 1);  // swizzled base, + kc*32 per k

    const float bh  = b_halt[0];
    const float bias0 = k0 ? (b_ih[jg]   + b_hh[jg])   : 0.0f;
    const float bias1 = k0 ? (b_ih[jg+1] + b_hh[jg+1]) : 0.0f;
    const float w0a   = k0 ? w_ih[jg*(NI+1)]     : 0.0f;
    const float w0b   = k0 ? w_ih[(jg+1)*(NI+1)] : 0.0f;

    // epilogue mapping: wave = row, lane = (ocol 0..15, kquarter 0..3)
    const int   eo = lb*16 + (lane & 15);
    const int   eq = lane >> 4;
    const int   eb = gp*16 + w;
    const float bo = b_out[eo];

    // decision mini-dot: wave w owns row gp*16+w; lane covers k = lane*16..+16.
    // Fixed reduction tree -> identical bits in every block.
    auto decide_p = [&](int slot) -> float {
        const float* hr = hbuf + slot*(NB*NH) + (gp*16 + w)*NH + lane*16;
        float d = 0.0f;
        #pragma unroll
        for (int q = 0; q < 16; q += 4) {
            const float4 hv = *(const float4*)(hr + q);
            const float4 wv = *(const float4*)(&s_whalt[lane*16 + q]);
            d += hv.x*wv.x + hv.y*wv.y + hv.z*wv.z + hv.w*wv.w;
        }
        d += __shfl_xor(d, 1);  d += __shfl_xor(d, 2);  d += __shfl_xor(d, 4);
        d += __shfl_xor(d, 8);  d += __shfl_xor(d, 16); d += __shfl_xor(d, 32);
        return 1.0f / (1.0f + expf(-(d + bh)));
    };

    unsigned gen = 0;
    int g = 0;                               // matmul counter -> hbuf slot rotation
    for (int t = 0; t < NT; ++t) {
        // -------- x-part partials (per-lane, unreduced; persist over ponder) ----
        float xw[4][2];
        xw[0][0]=bias0; xw[0][1]=bias1; xw[1][0]=bias0; xw[1][1]=bias1;
        xw[2][0]=bias0; xw[2][1]=bias1; xw[3][0]=bias0; xw[3][1]=bias1;
        {
            const float* xr0 = x + ((b0+0)*NT + t)*NI + ks*32;
            const float* xr1 = x + ((b0+1)*NT + t)*NI + ks*32;
            const float* xr2 = x + ((b0+2)*NT + t)*NI + ks*32;
            const float* xr3 = x + ((b0+3)*NT + t)*NI + ks*32;
            const float* wp  = wihT + (ks*32)*NH + jg;
            #pragma unroll 4
            for (int i = 0; i < 32; i += 4) {
                const float4 x0 = *(const float4*)(xr0 + i);
                const float4 x1 = *(const float4*)(xr1 + i);
                const float4 x2 = *(const float4*)(xr2 + i);
                const float4 x3 = *(const float4*)(xr3 + i);
                const float2 wa = *(const float2*)(wp + (i  )*NH);
                const float2 wb = *(const float2*)(wp + (i+1)*NH);
                const float2 wc = *(const float2*)(wp + (i+2)*NH);
                const float2 wd = *(const float2*)(wp + (i+3)*NH);
                xw[0][0] += x0.x*wa.x + x0.y*wb.x + x0.z*wc.x + x0.w*wd.x;
                xw[0][1] += x0.x*wa.y + x0.y*wb.y + x0.z*wc.y + x0.w*wd.y;
                xw[1][0] += x1.x*wa.x + x1.y*wb.x + x1.z*wc.x + x1.w*wd.x;
                xw[1][1] += x1.x*wa.y + x1.y*wb.y + x1.z*wc.y + x1.w*wd.y;
                xw[2][0] += x2.x*wa.x + x2.y*wb.x + x2.z*wc.x + x2.w*wd.x;
                xw[2][1] += x2.x*wa.y + x2.y*wb.y + x2.z*wc.y + x2.w*wd.y;
                xw[3][0] += x3.x*wa.x + x3.y*wb.x + x3.z*wc.x + x3.w*wd.x;
                xw[3][1] += x3.x*wa.y + x3.y*wb.y + x3.z*wc.y + x3.w*wd.y;
            }
        }

        auto hh_matmul = [&](const float* hsrc, float a[4][2]) {
            const float* hp0 = hsrc + (b0+0)*NH + ks*64;
            const float* hp1 = hsrc + (b0+1)*NH + ks*64;
            const float* hp2 = hsrc + (b0+2)*NH + ks*64;
            const float* hp3 = hsrc + (b0+3)*NH + ks*64;
            #pragma unroll 4
            for (int kc = 0; kc < 64; kc += 4) {
                const float4 h0 = *(const float4*)(hp0 + kc);
                const float4 h1 = *(const float4*)(hp1 + kc);
                const float4 h2 = *(const float4*)(hp2 + kc);
                const float4 h3 = *(const float4*)(hp3 + kc);
                const float2 wa = *(const float2*)(smem + ldsb + (kc  )*32);
                const float2 wb = *(const float2*)(smem + ldsb + (kc+1)*32);
                const float2 wc = *(const float2*)(smem + ldsb + (kc+2)*32);
                const float2 wd = *(const float2*)(smem + ldsb + (kc+3)*32);
                a[0][0] += h0.x*wa.x + h0.y*wb.x + h0.z*wc.x + h0.w*wd.x;
                a[0][1] += h0.x*wa.y + h0.y*wb.y + h0.z*wc.y + h0.w*wd.y;
                a[1][0] += h1.x*wa.x + h1.y*wb.x + h1.z*wc.x + h1.w*wd.x;
                a[1][1] += h1.x*wa.y + h1.y*wb.y + h1.z*wc.y + h1.w*wd.y;
                a[2][0] += h2.x*wa.x + h2.y*wb.x + h2.z*wc.x + h2.w*wd.x;
                a[2][1] += h2.x*wa.y + h2.y*wb.y + h2.z*wc.y + h2.w*wd.y;
                a[3][0] += h3.x*wa.x + h3.y*wb.x + h3.z*wc.x + h3.w*wd.x;
                a[3][1] += h3.x*wa.y + h3.y*wb.y + h3.z*wc.y + h3.w*wd.y;
            }
        };
        auto reduce8 = [&](float a[4][2]) {
            #pragma unroll
            for (int r = 0; r < 4; ++r)
                #pragma unroll
                for (int c = 0; c < 2; ++c) {
                    float v = a[r][c];
                    v += __shfl_xor(v, 4);  v += __shfl_xor(v, 8);
                    v += __shfl_xor(v, 16); v += __shfl_xor(v, 32);
                    a[r][c] = v;
                }
        };

        // -------- main step --------
        int sw = g % 3;
        {
            float a[4][2];
            a[0][0]=xw[0][0]+w0a; a[0][1]=xw[0][1]+w0b;
            a[1][0]=xw[1][0]+w0a; a[1][1]=xw[1][1]+w0b;
            a[2][0]=xw[2][0]+w0a; a[2][1]=xw[2][1]+w0b;
            a[3][0]=xw[3][0]+w0a; a[3][1]=xw[3][1]+w0b;
            const float* hc = (t == 0) ? s0 : (habuf + ((t-1)&1)*(NB*NH));
            hh_matmul(hc, a);
            reduce8(a);
            if (k0) {
                #pragma unroll
                for (int r = 0; r < 4; ++r) {
                    const float ha = tanhf(a[r][0]), hb = tanhf(a[r][1]);
                    float* hw = hbuf + sw*(NB*NH) + (b0+r)*NH + jg;
                    hw[0] = ha; hw[1] = hb;
                    float* hq = habuf + (t&1)*(NB*NH) + (b0+r)*NH + jg;
                    hq[0] = ha; hq[1] = hb;
                }
            }
        }
        ++g; ++gen; group_barrier(arr, lb, gen, tid);

        // -------- local decision from h1 (identical in all 32 blocks) --------
        float p = decide_p(sw);
        float cum_w = p;
        int   n_w   = 1;
        bool  act_w = (p < 0.99f);
        if (lb == 0 && lane == 0)
            out[PONDOFF + (gp*16 + w)*NT + t] = act_w ? 0.0f : 2.0f;
        if (lane == 0) s_act[w] = act_w ? 1 : 0;
        __syncthreads();
        int sprev = sw;

        // -------- ponder steps --------
        for (int s = 1; s <= 11; ++s) {
            const uint4 av = *(const uint4*)s_act;
            if (!(av.x | av.y | av.z | av.w)) break;
            const int a0 = s_act[rq*4+0], a1 = s_act[rq*4+1];
            const int a2 = s_act[rq*4+2], a3 = s_act[rq*4+3];
            sw = g % 3;
            if (a0|a1|a2|a3) {
                float a[4][2];
                a[0][0]=xw[0][0]; a[0][1]=xw[0][1]; a[1][0]=xw[1][0]; a[1][1]=xw[1][1];
                a[2][0]=xw[2][0]; a[2][1]=xw[2][1]; a[3][0]=xw[3][0]; a[3][1]=xw[3][1];
                hh_matmul(hbuf + sprev*(NB*NH), a);
                reduce8(a);
                if (k0) {
                    const int am[4] = {a0, a1, a2, a3};
                    #pragma unroll
                    for (int r = 0; r < 4; ++r) {
                        if (am[r]) {
                            const float ha = tanhf(a[r][0]), hb = tanhf(a[r][1]);
                            float* hw = hbuf + sw*(NB*NH) + (b0+r)*NH + jg;
                            hw[0] = ha; hw[1] = hb;
                            float* hq = habuf + (t&1)*(NB*NH) + (b0+r)*NH + jg;
                            hq[0] += ha; hq[1] += hb;
                        }
                    }
                }
            }
            ++g; ++gen; group_barrier(arr, lb, gen, tid);
            p = decide_p(sw);           // garbage for inactive rows; gated below
            if (act_w) {
                cum_w += p;
                n_w   += 1;
                act_w  = (cum_w < 0.99f);
            }
            if (lane == 0) s_act[w] = act_w ? 1 : 0;
            __syncthreads();
            sprev = sw;
        }

        // -------- epilogue: out = h_acc @ W_out^T + n*b_out --------
        {
            const float* ha = habuf + (t&1)*(NB*NH) + eb*NH + eq*256;
            const float* wq = w_out + eo*NH + eq*256;
            float acc = 0.0f;
            #pragma unroll 4
            for (int jj2 = 0; jj2 < 256; jj2 += 4) {
                const float4 hv = *(const float4*)(ha + jj2);
                const float4 wv = *(const float4*)(wq + jj2);
                acc += hv.x*wv.x + hv.y*wv.y + hv.z*wv.z + hv.w*wv.w;
            }
            acc += __shfl_xor(acc, 16); acc += __shfl_xor(acc, 32);
            if (eq == 0) out[(eb*NT + t)*NO + eo] = acc + (float)n_w*bo;
        }
        // safe without extra barrier: next main writes hbuf slot g%3 (readers
        // after the last barrier touch only slot (g-1)%3) and habuf parity
        // (t+1)&1 (epilogue reads (t&1)).
    }
}

extern "C" void kernel_launch(void* const* d_in, const int* in_sizes, int n_in,
                              void* d_out, int out_size, void* d_ws, size_t ws_size,
                              hipStream_t stream) {
    const float* x      = (const float*)d_in[0];
    const float* s0     = (const float*)d_in[1];
    const float* w_ih   = (const float*)d_in[2];
    const float* w_hh   = (const float*)d_in[3];
    const float* b_ih   = (const float*)d_in[4];
    const float* b_hh   = (const float*)d_in[5];
    const float* w_halt = (const float*)d_in[6];
    const float* b_halt = (const float*)d_in[7];
    const float* w_out  = (const float*)d_in[8];
    const float* b_out  = (const float*)d_in[9];
    float* out = (float*)d_out;
    float* ws  = (float*)d_ws;

    static const int kLds = 131072;
    hipFuncSetAttribute((const void*)arnn_coop,
                        hipFuncAttributeMaxDynamicSharedMemorySize, kLds);

    void* args[] = { (void*)&x, (void*)&s0, (void*)&w_ih, (void*)&w_hh,
                     (void*)&b_ih, (void*)&b_hh, (void*)&w_halt, (void*)&b_halt,
                     (void*)&w_out, (void*)&b_out, (void*)&out, (void*)&ws };
    hipLaunchCooperativeKernel((void*)arnn_coop, dim3(256), dim3(1024), args, kLds, stream);
}

// Round 5
// 9379.380 us; speedup vs baseline: 1.0837x; 1.0837x over previous
//
#include <hip/hip_runtime.h>
#include <hip/hip_cooperative_groups.h>
#include <math.h>

namespace cg = cooperative_groups;

#define NB 128      // batch
#define NT 64       // timesteps
#define NI 512      // input dim
#define NH 1024     // hidden dim
#define NO 512      // output dim
#define PONDOFF (NB*NT*NO)

// dynamic LDS: [1024][32] w_hh column-slice, XOR-swizzled, 128 KB
extern __shared__ float smem[];

// Per-group (32-block) barrier, v3: single monotonic arrival counter.
// Arrival: fetch_add(1, RELEASE) — publishes this block's stores (all waves'
// stores are already drained to L2 by the preceding __syncthreads).
// Poll: ONE leader lane fetch_add(0) (RMW executes at coherence point, always
// fresh). Acquire fence (L1+L2 inv) by wave 0 only — cache invalidates are
// physically CU/XCD-wide; __syncthreads orders the other waves behind it.
__device__ __forceinline__ void group_barrier(unsigned* ctr, unsigned target, int tid)
{
    __syncthreads();
    if (tid == 0) {
        __hip_atomic_fetch_add(ctr, 1u, __ATOMIC_RELEASE, __HIP_MEMORY_SCOPE_AGENT);
        while (__hip_atomic_fetch_add(ctr, 0u, __ATOMIC_RELAXED,
                                      __HIP_MEMORY_SCOPE_AGENT) < target)
            __builtin_amdgcn_s_sleep(1);
    }
    if (tid < 64)
        __builtin_amdgcn_fence(__ATOMIC_ACQUIRE, "agent");
    __syncthreads();
}

// 256 blocks x 1024 threads. 8 groups x 32 blocks; group owns 16 batch rows,
// block owns a 32-col slice. ASYNC ROW SCHEDULING: every interval, every
// unfinished row executes one step (main or ponder) at its OWN timestep;
// rows never wait for siblings. All 32 blocks replicate the (deterministic,
// bit-identical) decision state machine -> uniform control flow, barriers
// carry only h data + one arrival RMW.
__global__ void __launch_bounds__(1024, 1)
arnn_coop(const float* __restrict__ x, const float* __restrict__ s0,
          const float* __restrict__ w_ih, const float* __restrict__ w_hh,
          const float* __restrict__ b_ih, const float* __restrict__ b_hh,
          const float* __restrict__ w_halt, const float* __restrict__ b_halt,
          const float* __restrict__ w_out, const float* __restrict__ b_out,
          float* __restrict__ out, float* __restrict__ ws)
{
    cg::grid_group grid = cg::this_grid();
    const int tid = threadIdx.x;
    const int bid = blockIdx.x;
    const int gid = bid * 1024 + tid;

    // ws layout (floats)
    float* wihT  = ws;                       // [NI][NH]  wihT[i*NH+j] = w_ih[j][1+i]
    float* hbuf  = wihT + NI*NH;             // [NB][2][NH] per-row ping-pong h
    float* habuf = hbuf + NB*2*NH;           // [2][NB][NH] timestep-parity h_acc
    unsigned* ctrA = (unsigned*)(habuf + 2*NB*NH);  // [8][16] arrival ctrs, 64B pad

    const int gp = bid >> 5, lb = bid & 31;

    __shared__ float s_whalt[NH];            // 4 KB
    // per-row replicated state (identical in all 32 blocks of the group)
    __shared__ int   s_t[16];                // current timestep
    __shared__ float s_cum[16];
    __shared__ int   s_n[16];                // steps executed this timestep
    __shared__ int   s_et[16], s_en[16];     // pending epilogue: timestep, n
    __shared__ unsigned char s_sl[16];       // hbuf slot last written
    __shared__ unsigned char s_run[16];      // row still has steps to run
    __shared__ unsigned char s_mode[16];     // 0=main, 1=ponder (next step)
    __shared__ unsigned char s_epi[16];      // epilogue pending this interval
    __shared__ int s_alive;

    // ---- phase 0 ----
    for (int e = gid; e < NI*NH; e += 256*1024) {
        const int i = e >> 10, jj = e & 1023;
        wihT[e] = w_ih[jj*(NI+1) + 1 + i];
    }
    if (gid < 8*16)
        __hip_atomic_store(&ctrA[gid], 0u, __ATOMIC_RELAXED, __HIP_MEMORY_SCOPE_AGENT);
    // stage this block's w_hh column slice into LDS, XOR-swizzled:
    // element (k, j) at float offset k*32 + ((j>>1)^((k>>6)&15))*2 + (j&1)
    for (int e = tid; e < 1024*32; e += 1024) {
        const int k = e & 1023, jj = e >> 10;
        const float v = w_hh[(lb*32 + jj)*NH + k];
        const int su = (jj >> 1) ^ ((k >> 6) & 15);
        smem[k*32 + su*2 + (jj & 1)] = v;
    }
    s_whalt[tid & 1023] = w_halt[tid & 1023];
    if (tid < 16) {
        s_t[tid] = 0; s_cum[tid] = 0.0f; s_n[tid] = 0;
        s_et[tid] = 0; s_en[tid] = 0;
        s_sl[tid] = 0; s_run[tid] = 1; s_mode[tid] = 0; s_epi[tid] = 0;
    }
    if (tid == 0) s_alive = 1;
    grid.sync();

    unsigned* ctr = ctrA + gp*16;

    const int w    = tid >> 6;
    const int lane = tid & 63;
    const int rq   = w >> 2;                 // row quad 0..3
    const int co   = w & 3;                  // col octet 0..3
    const int up   = lane & 3;               // col pair in octet
    const int ks   = lane >> 2;              // k-slice 0..15 (64 wide)
    const int u    = co*4 + up;              // col pair in block 0..15
    const int jg   = lb*32 + u*2;            // global col (pair base)
    const int b0   = gp*16 + rq*4;           // first of my 4 matmul rows
    const bool k0  = (ks == 0);
    const int ldsb = ks*2048 + ((u ^ ks) << 1);

    const float bh  = b_halt[0];
    const float bias0 = k0 ? (b_ih[jg]   + b_hh[jg])   : 0.0f;
    const float bias1 = k0 ? (b_ih[jg+1] + b_hh[jg+1]) : 0.0f;
    const float w0a   = k0 ? w_ih[jg*(NI+1)]     : 0.0f;
    const float w0b   = k0 ? w_ih[(jg+1)*(NI+1)] : 0.0f;

    // epilogue mapping: wave = row, lane = (ocol 0..15, kquarter 0..3)
    const int   eo = lb*16 + (lane & 15);
    const int   eq = lane >> 4;
    const int   eb = gp*16 + w;
    const float bo = b_out[eo];

    // decision mini-dot: wave w owns row gp*16+w; fixed tree = identical bits
    auto decide_p = [&](int slot) -> float {
        const float* hr = hbuf + ((gp*16 + w)*2 + slot)*NH + lane*16;
        float d = 0.0f;
        #pragma unroll
        for (int q = 0; q < 16; q += 4) {
            const float4 hv = *(const float4*)(hr + q);
            const float4 wv = *(const float4*)(&s_whalt[lane*16 + q]);
            d += hv.x*wv.x + hv.y*wv.y + hv.z*wv.z + hv.w*wv.w;
        }
        d += __shfl_xor(d, 1);  d += __shfl_xor(d, 2);  d += __shfl_xor(d, 4);
        d += __shfl_xor(d, 8);  d += __shfl_xor(d, 16); d += __shfl_xor(d, 32);
        return 1.0f / (1.0f + expf(-(d + bh)));
    };

    float xw[4][2];                          // per-row x-part, persists over ponder

    unsigned gen = 0;
    for (;;) {
        // ================= compute phase =================
        // ---- epilogue for my decide-row, if pending ----
        if (s_epi[w]) {
            const int et = s_et[w];
            const float* ha = habuf + (et&1)*(NB*NH) + eb*NH + eq*256;
            const float* wq = w_out + eo*NH + eq*256;
            float acc = 0.0f;
            #pragma unroll 4
            for (int jj2 = 0; jj2 < 256; jj2 += 4) {
                const float4 hv = *(const float4*)(ha + jj2);
                const float4 wv = *(const float4*)(wq + jj2);
                acc += hv.x*wv.x + hv.y*wv.y + hv.z*wv.z + hv.w*wv.w;
            }
            acc += __shfl_xor(acc, 16); acc += __shfl_xor(acc, 32);
            if (eq == 0) out[(eb*NT + et)*NO + eo] = acc + (float)s_en[w]*bo;
        }
        // ---- one step for each of my 4 matmul rows ----
        int ex[4], md[4], tt[4], sl[4];
        #pragma unroll
        for (int r = 0; r < 4; ++r) {
            const int rr = rq*4 + r;
            ex[r] = s_run[rr]; md[r] = s_mode[rr]; tt[r] = s_t[rr]; sl[r] = s_sl[rr];
        }
        if (ex[0] | ex[1] | ex[2] | ex[3]) {
            // x-part for rows starting a timestep (wave-uniform branches)
            #pragma unroll
            for (int r = 0; r < 4; ++r) {
                if (ex[r] && md[r] == 0) {
                    float o0 = bias0, o1 = bias1;
                    const float* xr = x + ((b0+r)*NT + tt[r])*NI + ks*32;
                    const float* wp = wihT + (ks*32)*NH + jg;
                    #pragma unroll 4
                    for (int i = 0; i < 32; i += 4) {
                        const float4 xv = *(const float4*)(xr + i);
                        const float2 wa = *(const float2*)(wp + (i  )*NH);
                        const float2 wb = *(const float2*)(wp + (i+1)*NH);
                        const float2 wc = *(const float2*)(wp + (i+2)*NH);
                        const float2 wd = *(const float2*)(wp + (i+3)*NH);
                        o0 += xv.x*wa.x + xv.y*wb.x + xv.z*wc.x + xv.w*wd.x;
                        o1 += xv.x*wa.y + xv.y*wb.y + xv.z*wc.y + xv.w*wd.y;
                    }
                    xw[r][0] = o0; xw[r][1] = o1;
                }
            }
            // hh matmul: per-row source by mode; dead rows compute garbage (discarded)
            float a[4][2];
            const float* hp[4];
            #pragma unroll
            for (int r = 0; r < 4; ++r) {
                const int b = b0 + r;
                a[r][0] = xw[r][0] + (md[r] == 0 ? w0a : 0.0f);
                a[r][1] = xw[r][1] + (md[r] == 0 ? w0b : 0.0f);
                if (!ex[r])           hp[r] = hbuf + (b*2)*NH + ks*64;
                else if (md[r] == 0)  hp[r] = (tt[r] == 0 ? s0 + b*NH
                                              : habuf + ((tt[r]-1)&1)*(NB*NH) + b*NH) + ks*64;
                else                  hp[r] = hbuf + (b*2 + sl[r])*NH + ks*64;
            }
            #pragma unroll 4
            for (int kc = 0; kc < 64; kc += 4) {
                const float4 h0 = *(const float4*)(hp[0] + kc);
                const float4 h1 = *(const float4*)(hp[1] + kc);
                const float4 h2 = *(const float4*)(hp[2] + kc);
                const float4 h3 = *(const float4*)(hp[3] + kc);
                const float2 wa = *(const float2*)(smem + ldsb + (kc  )*32);
                const float2 wb = *(const float2*)(smem + ldsb + (kc+1)*32);
                const float2 wc = *(const float2*)(smem + ldsb + (kc+2)*32);
                const float2 wd = *(const float2*)(smem + ldsb + (kc+3)*32);
                a[0][0] += h0.x*wa.x + h0.y*wb.x + h0.z*wc.x + h0.w*wd.x;
                a[0][1] += h0.x*wa.y + h0.y*wb.y + h0.z*wc.y + h0.w*wd.y;
                a[1][0] += h1.x*wa.x + h1.y*wb.x + h1.z*wc.x + h1.w*wd.x;
                a[1][1] += h1.x*wa.y + h1.y*wb.y + h1.z*wc.y + h1.w*wd.y;
                a[2][0] += h2.x*wa.x + h2.y*wb.x + h2.z*wc.x + h2.w*wd.x;
                a[2][1] += h2.x*wa.y + h2.y*wb.y + h2.z*wc.y + h2.w*wd.y;
                a[3][0] += h3.x*wa.x + h3.y*wb.x + h3.z*wc.x + h3.w*wd.x;
                a[3][1] += h3.x*wa.y + h3.y*wb.y + h3.z*wc.y + h3.w*wd.y;
            }
            #pragma unroll
            for (int r = 0; r < 4; ++r)
                #pragma unroll
                for (int c = 0; c < 2; ++c) {
                    float v = a[r][c];
                    v += __shfl_xor(v, 4);  v += __shfl_xor(v, 8);
                    v += __shfl_xor(v, 16); v += __shfl_xor(v, 32);
                    a[r][c] = v;
                }
            if (k0) {
                #pragma unroll
                for (int r = 0; r < 4; ++r) {
                    if (ex[r]) {
                        const float ha = tanhf(a[r][0]), hb = tanhf(a[r][1]);
                        const int b = b0 + r;
                        float* hw = hbuf + (b*2 + (sl[r]^1))*NH + jg;
                        hw[0] = ha; hw[1] = hb;
                        float* hq = habuf + (tt[r]&1)*(NB*NH) + b*NH + jg;
                        if (md[r] == 0) { hq[0] = ha;  hq[1] = hb;  }
                        else            { hq[0] += ha; hq[1] += hb; }
                    }
                }
            }
        }
        // ================= barrier =================
        ++gen; group_barrier(ctr, 32*gen, tid);
        // ================= decide + state update (row w, bit-identical) ========
        const int exw = s_run[w];
        float p = 0.0f;
        if (exw) p = decide_p(s_sl[w] ^ 1);
        if (lane == 0) {
            int newepi = 0;
            if (exw) {
                const int t = s_t[w];
                float cum; int n;
                if (s_mode[w] == 0) {
                    cum = p; n = 1;
                    if (lb == 0) out[PONDOFF + (gp*16 + w)*NT + t] = (p >= 0.99f) ? 2.0f : 0.0f;
                } else {
                    cum = s_cum[w] + p; n = s_n[w] + 1;
                }
                s_cum[w] = cum; s_n[w] = n;
                s_sl[w] ^= 1;
                if ((cum < 0.99f) && n < 12) {
                    s_mode[w] = 1;
                } else {                     // timestep finished
                    newepi = 1; s_et[w] = t; s_en[w] = n;
                    if (t == NT-1) s_run[w] = 0;
                    else { s_t[w] = t + 1; s_mode[w] = 0; }
                }
            }
            s_epi[w] = newepi;
        }
        __syncthreads();
        if (w == 0) {
            const int al = (lane < 16) ? (s_run[lane] | s_epi[lane]) : 0;
            const unsigned long long m = __ballot(al);
            if (lane == 0) s_alive = (m != 0ULL) ? 1 : 0;
        }
        __syncthreads();
        if (!s_alive) break;
    }
}

extern "C" void kernel_launch(void* const* d_in, const int* in_sizes, int n_in,
                              void* d_out, int out_size, void* d_ws, size_t ws_size,
                              hipStream_t stream) {
    const float* x      = (const float*)d_in[0];
    const float* s0     = (const float*)d_in[1];
    const float* w_ih   = (const float*)d_in[2];
    const float* w_hh   = (const float*)d_in[3];
    const float* b_ih   = (const float*)d_in[4];
    const float* b_hh   = (const float*)d_in[5];
    const float* w_halt = (const float*)d_in[6];
    const float* b_halt = (const float*)d_in[7];
    const float* w_out  = (const float*)d_in[8];
    const float* b_out  = (const float*)d_in[9];
    float* out = (float*)d_out;
    float* ws  = (float*)d_ws;

    static const int kLds = 131072;
    hipFuncSetAttribute((const void*)arnn_coop,
                        hipFuncAttributeMaxDynamicSharedMemorySize, kLds);

    void* args[] = { (void*)&x, (void*)&s0, (void*)&w_ih, (void*)&w_hh,
                     (void*)&b_ih, (void*)&b_hh, (void*)&w_halt, (void*)&b_halt,
                     (void*)&w_out, (void*)&b_out, (void*)&out, (void*)&ws };
    hipLaunchCooperativeKernel((void*)arnn_coop, dim3(256), dim3(1024), args, kLds, stream);
}